// Round 2
// baseline (136.145 us; speedup 1.0000x reference)
//
#include <hip/hip_runtime.h>

// HMM posterior: out[b,t,s] = log_softmax_s(alphahat[t]+betahat[t]) — batch-independent
// (per-(b,t) scalar emission terms cancel in the state-axis softmax; observations unused).
// Linear space with max-rescale (scale cancels): p_t = p0 @ E^t, q_t = E^(T-1-t) @ 1, E=exp(A).
//
// SINGLE kernel (round-2): each of the 1024 blocks runs interleaved binary
// exponentiation entirely in LDS:
//   for k = 0..9: { if bit_k(t):      p ·= M[k]   (wave 0, Th/Tl planes)
//                   if bit_k(1023-t): q ·= M[k]^T (wave 1, Ah/Al planes)
//                   if k<9: M[k+1] = norm(M[k]^2) (all 4 waves, split-bf16 MFMA) }
// No global M/Mt, no separate powers kernel, no launch gap. Redundant squarings
// cost 1024×9×1.57 MFLOP ≈ 14.5 GFLOP ≈ 6 µs chip-wide — same wall time the old
// single-block hmm_powers took serially on ONE CU. Matvecs read hi+lo (≈ fp32 to
// 2^-17 rel; negligible vs the ~1e-5 split-bf16 squaring error).
// Every block needs all 9 squarings: max(t, 1023-t) ≥ 512, so bit 9 is always used.

#define TT 1024
#define NK 10
#define PS 72   // bf16 plane stride in ushorts (144 B rows: 16B-aligned, 2-way banks = free)

typedef short  bf16x8 __attribute__((ext_vector_type(8)));
typedef float  f32x4  __attribute__((ext_vector_type(4)));

__device__ __forceinline__ unsigned short f2bf(float x) {
    unsigned u = __float_as_uint(x);
    unsigned r = u + 0x7fffu + ((u >> 16) & 1u);   // RNE; inputs finite
    return (unsigned short)(r >> 16);
}
__device__ __forceinline__ float bf2f(unsigned short h) {
    return __uint_as_float(((unsigned)h) << 16);
}

__global__ __launch_bounds__(256) void hmm_all(const float* __restrict__ logA,
                                               const float* __restrict__ logInit,
                                               float* __restrict__ out) {
    __shared__ unsigned short Ah[64 * PS], Al[64 * PS];   // row-major hi/lo planes
    __shared__ unsigned short Th[64 * PS], Tl[64 * PS];   // transposed hi/lo planes
    __shared__ float red4[4];
    __shared__ float sp[64], sq[64], sgr[64];
    const int t    = blockIdx.x;
    const int tid  = threadIdx.x;
    const int wid  = tid >> 6;
    const int lane = tid & 63;

    // ---- Phase 0: E0 = exp(logA), normalized by max entry -> hi/lo planes (LDS only).
    {
        const int row = tid >> 2;
        const int c0  = (tid & 3) * 16;
        float v[16];
        float lmax = 0.f;
        #pragma unroll
        for (int jj = 0; jj < 4; ++jj) {
            float4 x = ((const float4*)logA)[row * 16 + (tid & 3) * 4 + jj];
            float e0 = __expf(x.x), e1 = __expf(x.y), e2 = __expf(x.z), e3 = __expf(x.w);
            v[4 * jj + 0] = e0; v[4 * jj + 1] = e1; v[4 * jj + 2] = e2; v[4 * jj + 3] = e3;
            lmax = fmaxf(lmax, fmaxf(fmaxf(e0, e1), fmaxf(e2, e3)));
        }
        #pragma unroll
        for (int off = 32; off > 0; off >>= 1)
            lmax = fmaxf(lmax, __shfl_xor(lmax, off, 64));
        if (lane == 0) red4[wid] = lmax;
        __syncthreads();
        const float sc = 1.f / fmaxf(fmaxf(red4[0], red4[1]), fmaxf(red4[2], red4[3]));
        #pragma unroll
        for (int j = 0; j < 16; ++j) {
            float val = v[j] * sc;
            unsigned short hi = f2bf(val);
            unsigned short lo = f2bf(val - bf2f(hi));
            int cc = c0 + j;
            Ah[row * PS + cc] = hi;  Al[row * PS + cc] = lo;
            Th[cc * PS + row] = hi;  Tl[cc * PS + row] = lo;
        }
    }
    if (tid < 64)        sp[tid]      = __expf(logInit[tid]);
    else if (tid < 128)  sq[tid - 64] = 1.f;

    const int quad = lane >> 4;
    const int l15  = lane & 15;
    const int ep   = t;
    const int eq   = (TT - 1) - t;

    for (int k = 0; k < NK; ++k) {
        __syncthreads();                 // planes hold M[k]; sp/sq stable

        // ---- matvec on M[k]: wave 0 -> p (cols of M = rows of Th), wave 1 -> q (rows of Ah).
        if (wid == 0) {
            if ((ep >> k) & 1) {
                float aacc[4] = {0.f, 0.f, 0.f, 0.f};
                const unsigned short* hr = &Th[lane * PS];
                const unsigned short* lr = &Tl[lane * PS];
                #pragma unroll
                for (int ii = 0; ii < 8; ++ii) {
                    bf16x8 h8 = *(const bf16x8*)(hr + 8 * ii);
                    bf16x8 l8 = *(const bf16x8*)(lr + 8 * ii);
                    float4 sa = ((const float4*)sp)[2 * ii];
                    float4 sb = ((const float4*)sp)[2 * ii + 1];
                    aacc[ii >> 1] = fmaf(sa.x, bf2f((unsigned short)h8[0]) + bf2f((unsigned short)l8[0]), aacc[ii >> 1]);
                    aacc[ii >> 1] = fmaf(sa.y, bf2f((unsigned short)h8[1]) + bf2f((unsigned short)l8[1]), aacc[ii >> 1]);
                    aacc[ii >> 1] = fmaf(sa.z, bf2f((unsigned short)h8[2]) + bf2f((unsigned short)l8[2]), aacc[ii >> 1]);
                    aacc[ii >> 1] = fmaf(sa.w, bf2f((unsigned short)h8[3]) + bf2f((unsigned short)l8[3]), aacc[ii >> 1]);
                    aacc[ii >> 1] = fmaf(sb.x, bf2f((unsigned short)h8[4]) + bf2f((unsigned short)l8[4]), aacc[ii >> 1]);
                    aacc[ii >> 1] = fmaf(sb.y, bf2f((unsigned short)h8[5]) + bf2f((unsigned short)l8[5]), aacc[ii >> 1]);
                    aacc[ii >> 1] = fmaf(sb.z, bf2f((unsigned short)h8[6]) + bf2f((unsigned short)l8[6]), aacc[ii >> 1]);
                    aacc[ii >> 1] = fmaf(sb.w, bf2f((unsigned short)h8[7]) + bf2f((unsigned short)l8[7]), aacc[ii >> 1]);
                }
                float accv = (aacc[0] + aacc[1]) + (aacc[2] + aacc[3]);
                float mx = accv;
                #pragma unroll
                for (int off = 32; off > 0; off >>= 1)
                    mx = fmaxf(mx, __shfl_xor(mx, off, 64));
                sp[lane] = accv * (1.f / mx);
            }
        } else if (wid == 1) {
            if ((eq >> k) & 1) {
                float aacc[4] = {0.f, 0.f, 0.f, 0.f};
                const unsigned short* hr = &Ah[lane * PS];
                const unsigned short* lr = &Al[lane * PS];
                #pragma unroll
                for (int ii = 0; ii < 8; ++ii) {
                    bf16x8 h8 = *(const bf16x8*)(hr + 8 * ii);
                    bf16x8 l8 = *(const bf16x8*)(lr + 8 * ii);
                    float4 sa = ((const float4*)sq)[2 * ii];
                    float4 sb = ((const float4*)sq)[2 * ii + 1];
                    aacc[ii >> 1] = fmaf(sa.x, bf2f((unsigned short)h8[0]) + bf2f((unsigned short)l8[0]), aacc[ii >> 1]);
                    aacc[ii >> 1] = fmaf(sa.y, bf2f((unsigned short)h8[1]) + bf2f((unsigned short)l8[1]), aacc[ii >> 1]);
                    aacc[ii >> 1] = fmaf(sa.z, bf2f((unsigned short)h8[2]) + bf2f((unsigned short)l8[2]), aacc[ii >> 1]);
                    aacc[ii >> 1] = fmaf(sa.w, bf2f((unsigned short)h8[3]) + bf2f((unsigned short)l8[3]), aacc[ii >> 1]);
                    aacc[ii >> 1] = fmaf(sb.x, bf2f((unsigned short)h8[4]) + bf2f((unsigned short)l8[4]), aacc[ii >> 1]);
                    aacc[ii >> 1] = fmaf(sb.y, bf2f((unsigned short)h8[5]) + bf2f((unsigned short)l8[5]), aacc[ii >> 1]);
                    aacc[ii >> 1] = fmaf(sb.z, bf2f((unsigned short)h8[6]) + bf2f((unsigned short)l8[6]), aacc[ii >> 1]);
                    aacc[ii >> 1] = fmaf(sb.w, bf2f((unsigned short)h8[7]) + bf2f((unsigned short)l8[7]), aacc[ii >> 1]);
                }
                float accv = (aacc[0] + aacc[1]) + (aacc[2] + aacc[3]);
                float mx = accv;
                #pragma unroll
                for (int off = 32; off > 0; off >>= 1)
                    mx = fmaxf(mx, __shfl_xor(mx, off, 64));
                sq[lane] = accv * (1.f / mx);
            }
        }
        if (k == NK - 1) break;

        __syncthreads();                 // matvec plane-reads + sp/sq writes done

        // ---- squaring: M[k+1] = norm(M[k]^2), split-bf16 MFMA (24/wave), all 4 waves.
        f32x4 acc[4];
        #pragma unroll
        for (int c = 0; c < 4; ++c) acc[c] = (f32x4){0.f, 0.f, 0.f, 0.f};
        #pragma unroll
        for (int kk = 0; kk < 2; ++kk) {
            const int ao = (16 * wid + l15) * PS + 32 * kk + quad * 8;
            bf16x8 ah = *(const bf16x8*)&Ah[ao];
            bf16x8 al = *(const bf16x8*)&Al[ao];
            #pragma unroll
            for (int c = 0; c < 4; ++c) {
                const int bo = (16 * c + l15) * PS + 32 * kk + quad * 8;
                bf16x8 bh = *(const bf16x8*)&Th[bo];
                bf16x8 bl = *(const bf16x8*)&Tl[bo];
                acc[c] = __builtin_amdgcn_mfma_f32_16x16x32_bf16(ah, bh, acc[c], 0, 0, 0);
                acc[c] = __builtin_amdgcn_mfma_f32_16x16x32_bf16(ah, bl, acc[c], 0, 0, 0);
                acc[c] = __builtin_amdgcn_mfma_f32_16x16x32_bf16(al, bh, acc[c], 0, 0, 0);
            }
        }
        float m = 0.f;
        #pragma unroll
        for (int c = 0; c < 4; ++c)
            #pragma unroll
            for (int r = 0; r < 4; ++r) m = fmaxf(m, acc[c][r]);
        #pragma unroll
        for (int off = 32; off > 0; off >>= 1)
            m = fmaxf(m, __shfl_xor(m, off, 64));
        if (lane == 0) red4[wid] = m;
        __syncthreads();                 // frag reads done by all waves; red4 ready
        const float sc = 1.f / fmaxf(fmaxf(red4[0], red4[1]), fmaxf(red4[2], red4[3]));
        #pragma unroll
        for (int c = 0; c < 4; ++c) {
            #pragma unroll
            for (int r = 0; r < 4; ++r) {
                float val = acc[c][r] * sc;
                const int rr = 16 * wid + quad * 4 + r;   // C/D: row = quad*4+reg (m89)
                const int cc = 16 * c   + l15;            //      col = lane&15
                unsigned short hi = f2bf(val);
                unsigned short lo = f2bf(val - bf2f(hi));
                Ah[rr * PS + cc] = hi;  Al[rr * PS + cc] = lo;
                Th[cc * PS + rr] = hi;  Tl[cc * PS + rr] = lo;
            }
        }
    }

    __syncthreads();                     // sp (wave 0) and sq (wave 1) both final

    if (wid == 0) {
        float gv = __logf(sp[lane]) + __logf(sq[lane]);
        float mx = gv;
        #pragma unroll
        for (int off = 32; off > 0; off >>= 1)
            mx = fmaxf(mx, __shfl_xor(mx, off, 64));
        float ex = __expf(gv - mx);
        float sm = ex;
        #pragma unroll
        for (int off = 32; off > 0; off >>= 1)
            sm += __shfl_xor(sm, off, 64);
        sgr[lane] = gv - mx - __logf(sm);
    }
    __syncthreads();

    // Broadcast row t to all 256 batches: out[b][t][0..63], float4, 256 threads x 16 stores.
    const int s4 = tid & 15;
    const int b0 = tid >> 4;                 // 0..15
    float4 val = ((const float4*)sgr)[s4];
    float4* o4 = (float4*)out;
    const size_t trow = (size_t)t * 16 + s4;
    #pragma unroll
    for (int it = 0; it < 16; ++it) {
        int b = (it << 4) + b0;
        o4[(size_t)b * 16384 + trow] = val;
    }
}

extern "C" void kernel_launch(void* const* d_in, const int* in_sizes, int n_in,
                              void* d_out, int out_size, void* d_ws, size_t ws_size,
                              hipStream_t stream) {
    // inputs: [0] observations (unused), [1] log_transition (64x64 f32),
    //         [2] log_initial (64 f32), [3] log_emission (unused)
    const float* logA    = (const float*)d_in[1];
    const float* logInit = (const float*)d_in[2];
    (void)d_ws; (void)ws_size;
    hmm_all<<<TT, 256, 0, stream>>>(logA, logInit, (float*)d_out);
}